// Round 3
// baseline (105.413 us; speedup 1.0000x reference)
//
#include <hip/hip_runtime.h>

// FOFE windowed encoder.
// x: (B=8, C=512, L=512) f32, alpha: (C,1) f32, out: (B, C, 49, 513) f32.
// out[b,c,i,t] = z[t-1] - alpha^{w_i} * z[t-1-w_i],  z[t] = alpha*z[t-1] + x[t]
// windows w_i = 0..47 and 64.

#define CC 512
#define LL 512
#define NW 49
#define LO 513
#define NPAD 65   // zeros in front of z so z[t-1-w] reads in-bounds (w<=64)
#define ZSZ 640   // swizzled storage upper bound for 577 logical slots

typedef float f32x4 __attribute__((ext_vector_type(4)));

// XOR-swizzle: lanes read z at stride 4 (float4 outputs) -> bits [2:4] of the
// word index vary -> only 8 banks -> 8-way conflict. Injecting bits [5:6]
// into bank bits [0:1] makes all 32 banks hit, 2 lanes/bank (free, m136).
__device__ __forceinline__ int swz(int i) { return i ^ ((i >> 5) & 3); }

__global__ __launch_bounds__(256, 8)
void fofe_kernel(const float* __restrict__ x,
                 const float* __restrict__ alpha,
                 float* __restrict__ out)
{
    // 4 waves per block; waves (0,1) -> row0, waves (2,3) -> row1.
    // Each wave has a PRIVATE z copy -> no __syncthreads anywhere.
    __shared__ float zp[4][ZSZ];

    const int tid  = threadIdx.x;
    const int wid  = tid >> 6;
    const int lane = tid & 63;
    const int row  = blockIdx.x * 2 + (wid >> 1);   // b*C + c
    const int half = wid & 1;                        // window parity
    const int c    = row & (CC - 1);

    const float al = alpha[c];
    const float* xr = x + (size_t)row * LL;

    // ---------- phase 1: linear-recurrence scan (chunk 8/lane) ----------
    const f32x4 xv0 = reinterpret_cast<const f32x4*>(xr)[lane * 2];
    const f32x4 xv1 = reinterpret_cast<const f32x4*>(xr)[lane * 2 + 1];
    const float xe[8] = {xv0.x, xv0.y, xv0.z, xv0.w,
                         xv1.x, xv1.y, xv1.z, xv1.w};

    float l[8];
    {
        float s = 0.f;
        #pragma unroll
        for (int m = 0; m < 8; ++m) { s = fmaf(al, s, xe[m]); l[m] = s; }
    }
    float pw[8];                       // alpha^{m+1}
    {
        float p = al;
        #pragma unroll
        for (int m = 0; m < 8; ++m) { pw[m] = p; p *= al; }
    }

    // wave-level inclusive scan of (A = alpha^8, S = chunk sum)
    float A = pw[7];
    float S = l[7];
    #pragma unroll
    for (int off = 1; off < 64; off <<= 1) {
        const float Ap = __shfl_up(A, off);
        const float Sp = __shfl_up(S, off);
        if (lane >= off) { S = fmaf(A, Sp, S); A = A * Ap; }
    }
    float carry = __shfl_up(S, 1);     // z at end of previous chunk
    if (lane == 0) carry = 0.f;

    float* z = zp[wid];
    z[swz(lane)] = 0.f;                // z[-65..-2]
    if (lane == 0) z[swz(64)] = 0.f;   // z[-1]
    #pragma unroll
    for (int m = 0; m < 8; ++m)
        z[swz(NPAD + lane * 8 + m)] = fmaf(pw[m], carry, l[m]);
    // wave-private LDS: hw keeps same-wave DS ops ordered; no barrier needed.

    // ---------- phase 2: stream the 49 window rows, aligned float4 ----------
    const float al2 = al * al;
    const float a4  = al2 * al2;
    const float a8  = a4 * a4;
    const float a16 = a8 * a8;
    const float a64 = (a16 * a16) * (a16 * a16);
    float ap = half ? al : 1.0f;       // alpha^i, stepped by alpha^2

    float* orow = out + (size_t)row * (NW * LO);

    for (int i = half; i < NW; i += 2) {
        const int   w   = (i < 48) ? i : 64;
        const float apw = (i < 48) ? ap : a64;
        float* op = orow + i * LO;
        // element phase of op: (row*25137 + i*513) mod 4 == (row + i) & 3
        const int q    = (row + i) & 3;
        const int peel = (4 - q) & 3;
        const int zb0  = NPAD - 1;     // + t gives z[t-1]

        if (lane < peel) {
            const int t = lane;
            op[t] = fmaf(-apw, z[swz(zb0 + t - w)], z[swz(zb0 + t)]);
        }

        const int nf4  = (LO - peel) >> 2;   // 127 or 128
        const int tail = (LO - peel) & 3;
        for (int f = lane; f < nf4; f += 64) {
            const int t0 = peel + 4 * f;
            f32x4 v;
            v.x = fmaf(-apw, z[swz(zb0 + t0     - w)], z[swz(zb0 + t0    )]);
            v.y = fmaf(-apw, z[swz(zb0 + t0 + 1 - w)], z[swz(zb0 + t0 + 1)]);
            v.z = fmaf(-apw, z[swz(zb0 + t0 + 2 - w)], z[swz(zb0 + t0 + 2)]);
            v.w = fmaf(-apw, z[swz(zb0 + t0 + 3 - w)], z[swz(zb0 + t0 + 3)]);
            // 412 MB streaming write, no reuse -> bypass L2 allocation
            __builtin_nontemporal_store(v, reinterpret_cast<f32x4*>(op + t0));
        }

        if (lane < tail) {
            const int t = peel + 4 * nf4 + lane;
            op[t] = fmaf(-apw, z[swz(zb0 + t - w)], z[swz(zb0 + t)]);
        }
        ap *= al2;
    }
}

extern "C" void kernel_launch(void* const* d_in, const int* in_sizes, int n_in,
                              void* d_out, int out_size, void* d_ws, size_t ws_size,
                              hipStream_t stream)
{
    const float* x     = (const float*)d_in[0];
    const float* alpha = (const float*)d_in[1];
    float* out = (float*)d_out;

    const int rows = 8 * CC;           // 4096
    const int grid = rows / 2;         // 2 rows per block
    fofe_kernel<<<grid, 256, 0, stream>>>(x, alpha, out);
}

// Round 4
// 90.999 us; speedup vs baseline: 1.1584x; 1.1584x over previous
//
#include <hip/hip_runtime.h>

// FOFE windowed encoder.
// x: (B=8, C=512, L=512) f32, alpha: (C,1) f32, out: (B, C, 49, 513) f32.
// out[b,c,i,t] = z[t-1] - alpha^{w_i} * z[t-1-w_i],  z[t] = alpha*z[t-1] + x[t]
// windows w_i = 0..47 and 64.

#define CC 512
#define LL 512
#define NW 49
#define LO 513
#define NPAD 65   // zeros in front of z so z[t-1-w] reads in-bounds (w<=64)
#define ZSZ 640   // swizzled storage upper bound for 577 logical slots

typedef float f32x4 __attribute__((ext_vector_type(4)));

// XOR-swizzle: lanes read z at stride 4 (float4 outputs) -> bits [2:4] of the
// word index vary -> only 8 banks -> 8-way conflict. Injecting bits [5:6]
// into bank bits [0:1] makes all 32 banks hit, 2 lanes/bank (free, m136).
// Involution + bijection on [0, ZSZ).
__device__ __forceinline__ int swz(int i) { return i ^ ((i >> 5) & 3); }

__global__ __launch_bounds__(256, 4)
void fofe_kernel(const float* __restrict__ x,
                 const float* __restrict__ alpha,
                 float* __restrict__ out)
{
    // 4 waves per block; waves (0,1) -> row0, waves (2,3) -> row1.
    // Each wave has a PRIVATE z copy -> no __syncthreads anywhere.
    __shared__ float zp[4][ZSZ];

    const int tid  = threadIdx.x;
    const int wid  = tid >> 6;
    const int lane = tid & 63;
    const int row  = blockIdx.x * 2 + (wid >> 1);   // b*C + c
    const int half = wid & 1;                        // window parity
    const int c    = row & (CC - 1);

    const float al = alpha[c];
    const float* xr = x + (size_t)row * LL;

    // ---------- phase 1: linear-recurrence scan (chunk 8/lane) ----------
    const f32x4 xv0 = reinterpret_cast<const f32x4*>(xr)[lane * 2];
    const f32x4 xv1 = reinterpret_cast<const f32x4*>(xr)[lane * 2 + 1];
    const float xe[8] = {xv0.x, xv0.y, xv0.z, xv0.w,
                         xv1.x, xv1.y, xv1.z, xv1.w};

    float l[8];
    {
        float s = 0.f;
        #pragma unroll
        for (int m = 0; m < 8; ++m) { s = fmaf(al, s, xe[m]); l[m] = s; }
    }
    float pw[8];                       // alpha^{m+1}
    {
        float p = al;
        #pragma unroll
        for (int m = 0; m < 8; ++m) { pw[m] = p; p *= al; }
    }

    // wave-level inclusive scan of (A = alpha^8, S = chunk sum)
    float A = pw[7];
    float S = l[7];
    #pragma unroll
    for (int off = 1; off < 64; off <<= 1) {
        const float Ap = __shfl_up(A, off);
        const float Sp = __shfl_up(S, off);
        if (lane >= off) { S = fmaf(A, Sp, S); A = A * Ap; }
    }
    float carry = __shfl_up(S, 1);     // z at end of previous chunk
    if (lane == 0) carry = 0.f;

    float* z = zp[wid];
    z[swz(lane)] = 0.f;                // z[-65..-2]
    if (lane == 0) z[swz(64)] = 0.f;   // z[-1]
    #pragma unroll
    for (int m = 0; m < 8; ++m)
        z[swz(NPAD + lane * 8 + m)] = fmaf(pw[m], carry, l[m]);
    // wave-private LDS: hw keeps same-wave DS ops ordered; no barrier needed.

    // ---------- phase 2: stream the 49 window rows, aligned float4 ----------
    const float al2 = al * al;
    const float a4  = al2 * al2;
    const float a8  = a4 * a4;
    const float a16 = a8 * a8;
    const float a64 = (a16 * a16) * (a16 * a16);
    float ap = half ? al : 1.0f;       // alpha^i, stepped by alpha^2

    float* orow = out + (size_t)row * (NW * LO);

    for (int i = half; i < NW; i += 2) {
        const int   w   = (i < 48) ? i : 64;
        const float apw = (i < 48) ? ap : a64;
        float* op = orow + i * LO;
        // element phase of op: (row*25137 + i*513) mod 4 == (row + i) & 3
        const int q    = (row + i) & 3;
        const int peel = (4 - q) & 3;
        const int zb0  = NPAD - 1;     // + t gives z[t-1]

        if (lane < peel) {
            const int t = lane;
            op[t] = fmaf(-apw, z[swz(zb0 + t - w)], z[swz(zb0 + t)]);
        }

        const int nf4  = (LO - peel) >> 2;   // 127 or 128
        const int tail = (LO - peel) & 3;
        for (int f = lane; f < nf4; f += 64) {
            const int t0 = peel + 4 * f;
            f32x4 v;
            v.x = fmaf(-apw, z[swz(zb0 + t0     - w)], z[swz(zb0 + t0    )]);
            v.y = fmaf(-apw, z[swz(zb0 + t0 + 1 - w)], z[swz(zb0 + t0 + 1)]);
            v.z = fmaf(-apw, z[swz(zb0 + t0 + 2 - w)], z[swz(zb0 + t0 + 2)]);
            v.w = fmaf(-apw, z[swz(zb0 + t0 + 3 - w)], z[swz(zb0 + t0 + 3)]);
            // normal cached store: let L2 assemble full lines (nt regressed, R2)
            *reinterpret_cast<f32x4*>(op + t0) = v;
        }

        if (lane < tail) {
            const int t = peel + 4 * nf4 + lane;
            op[t] = fmaf(-apw, z[swz(zb0 + t - w)], z[swz(zb0 + t)]);
        }
        ap *= al2;
    }
}

extern "C" void kernel_launch(void* const* d_in, const int* in_sizes, int n_in,
                              void* d_out, int out_size, void* d_ws, size_t ws_size,
                              hipStream_t stream)
{
    const float* x     = (const float*)d_in[0];
    const float* alpha = (const float*)d_in[1];
    float* out = (float*)d_out;

    const int rows = 8 * CC;           // 4096
    const int grid = rows / 2;         // 2 rows per block
    fofe_kernel<<<grid, 256, 0, stream>>>(x, alpha, out);
}